// Round 8
// baseline (645.804 us; speedup 1.0000x reference)
//
#include <hip/hip_runtime.h>
#include <hip/hip_fp16.h>
#include <math.h>

#define N_NODES 100000
#define N_EDGES 1600000
#define F_IN 15
#define NB_NODES 391   // ceil(N_NODES/256)
#define MASK40 ((1ull << 40) - 1)

typedef _Float16 half8 __attribute__((ext_vector_type(8)));
typedef float f32x4 __attribute__((ext_vector_type(4)));

// ---------------- prelude (single-copy: R7 showed XCD replication buys 0) ----

__global__ void k_initp(unsigned long long* __restrict__ packed) {
    int i = blockIdx.x * blockDim.x + threadIdx.x;
    if (i < N_NODES) packed[i] = 0ull;
}

// one packed 64-bit atomic per edge: count in [40..], weight-sum 32.8fx below.
// Returned old count = this edge's CSR ordinal. 1 atomic/edge = structural min.
__global__ void k_cnt(const int* __restrict__ dst, const float* __restrict__ w,
                      unsigned long long* __restrict__ packed, int* __restrict__ ord) {
    int i = blockIdx.x * blockDim.x + threadIdx.x;
    if (i >= N_EDGES) return;
    int d = dst[i];
    unsigned long long contrib =
        (1ull << 40) + (unsigned long long)((double)w[i] * 4294967296.0);
    unsigned long long old = atomicAdd(&packed[d], contrib);
    ord[i] = (int)(old >> 40);
}

__global__ void k_part(const unsigned long long* __restrict__ packed,
                       int* __restrict__ bsum, float* __restrict__ dinv) {
    __shared__ int red[256];
    int t = threadIdx.x;
    int i = blockIdx.x * 256 + t;
    int c = 0;
    if (i < N_NODES) {
        unsigned long long p = packed[i];
        c = (int)(p >> 40);
        float deg = 1.0f + (float)((double)(p & MASK40) * 0x1p-32);
        dinv[i] = rsqrtf(deg);
    }
    red[t] = c;
    __syncthreads();
    for (int off = 128; off > 0; off >>= 1) {
        if (t < off) red[t] += red[t + off];
        __syncthreads();
    }
    if (t == 0) bsum[blockIdx.x] = red[0];
}

__global__ __launch_bounds__(512) void k_scanb(int* __restrict__ bsum,
                                               int* __restrict__ rowptr) {
    __shared__ int sc[512];
    int t = threadIdx.x;
    int v = (t < NB_NODES) ? bsum[t] : 0;
    sc[t] = v;
    __syncthreads();
    for (int off = 1; off < 512; off <<= 1) {
        int u = (t >= off) ? sc[t - off] : 0;
        __syncthreads();
        sc[t] += u;
        __syncthreads();
    }
    if (t < NB_NODES) bsum[t] = sc[t] - v;
    if (t == 0) rowptr[N_NODES] = N_EDGES;
}

__global__ void k_fillptr(const unsigned long long* __restrict__ packed,
                          const int* __restrict__ bsum, int* __restrict__ rowptr) {
    __shared__ int sc[256];
    int t = threadIdx.x;
    int i = blockIdx.x * 256 + t;
    int v = (i < N_NODES) ? (int)(packed[i] >> 40) : 0;
    sc[t] = v;
    __syncthreads();
    for (int off = 1; off < 256; off <<= 1) {
        int u = (t >= off) ? sc[t - off] : 0;
        __syncthreads();
        sc[t] += u;
        __syncthreads();
    }
    if (i < N_NODES) rowptr[i] = bsum[blockIdx.x] + sc[t] - v;
}

__global__ void k_fill(const int* __restrict__ src, const int* __restrict__ dst,
                       const float* __restrict__ w, const float* __restrict__ dinv,
                       const int* __restrict__ rowptr, const int* __restrict__ ord,
                       int2* __restrict__ csr) {
    int i = blockIdx.x * blockDim.x + threadIdx.x;
    if (i >= N_EDGES) return;
    int s = src[i], d = dst[i];
    float nm = dinv[s] * w[i] * dinv[d];
    csr[rowptr[d] + ord[i]] = make_int2(s, __float_as_int(nm));
}

// ---------------- W prep: transposed n-major fp16 hi/lo split, once ----------
// wt_hi/wt_lo[l][n][k], l in [0,7): l<6 = Wm, l=6 = Wl. Epilogue then loads
// B-frags as contiguous half8 (k runs fastest) with zero per-layer VALU split.

__global__ void k_prepw(const float* __restrict__ Wm, const float* __restrict__ Wl,
                        _Float16* __restrict__ wt_hi, _Float16* __restrict__ wt_lo) {
    int i = blockIdx.x * blockDim.x + threadIdx.x;   // over 7*4096
    if (i >= 7 * 4096) return;
    int l = i >> 12, n = (i >> 6) & 63, k = i & 63;
    float w = (l < 6) ? Wm[l * 4096 + k * 64 + n] : Wl[k * 64 + n];
    _Float16 hi = (_Float16)w;
    wt_hi[i] = hi;
    wt_lo[i] = (_Float16)(w - (float)hi);
}

// ---------------- layer 0 dense transform: [N,15]@[15,64] -> fp16 ------------

__global__ void k_gemm0(const float* __restrict__ x, const float* __restrict__ W,
                        __half* __restrict__ out) {
    __shared__ float Ws[F_IN * 64];
    int t = threadIdx.x;
    for (int i = t; i < F_IN * 64; i += 256) Ws[i] = W[i];
    __syncthreads();
    int r = blockIdx.x * 4 + (t >> 6);
    int c = t & 63;
    if (r < N_NODES) {
        const float* xr = x + (long)r * F_IN;
        float acc = 0.f;
#pragma unroll
        for (int k = 0; k < F_IN; k++) acc += xr[k] * Ws[k * 64 + c];
        out[(long)r * 64 + c] = __float2half(acc);
    }
}

// ---------------- fused aggregation + MFMA dense epilogue --------------------
// hin stored POST-activation. Wave = 8 nodes; lane = (sub: edge-of-pair) x
// (fl: feature pair). Records LDS-staged. 4-edge main unroll (2 loads/lane in
// flight; 32 waves/CU x 2 = 64 lines in flight > ~33 needed for LLC BW-delay).

#define SE_CAP 256
#define G_STRIDE 72

template <bool WEP, bool SIG>
__global__ __launch_bounds__(256) void k_gather5(
        const int* __restrict__ rowptr, const int2* __restrict__ csr,
        const __half* __restrict__ hin, const float* __restrict__ dinv,
        const _Float16* __restrict__ whi, const _Float16* __restrict__ wlo,
        const float* __restrict__ b, void* __restrict__ outp) {
    extern __shared__ char smem[];
    int t = threadIdx.x, wv = t >> 6, lane = t & 63;
    int sub = lane >> 5, fl = lane & 31;
    int2* se = (int2*)smem + wv * SE_CAP;
    _Float16* G = (_Float16*)(smem + 4 * SE_CAP * 8);

    int nb = blockIdx.x * 32;
    int n0w = nb + wv * 8;

    int rp[9];
#pragma unroll
    for (int j = 0; j < 9; j++) rp[j] = rowptr[n0w + j];
    int base = rp[0], end = rp[8];

    const __half2* h2 = (const __half2*)hin;

    float2 acc[8];
#pragma unroll
    for (int j = 0; j < 8; j++) {
        int n = n0w + j;
        float dv = dinv[n];
        float2 hf = __half22float2(h2[(long)n * 32 + fl]);
        float w0 = (sub == 0) ? dv * dv : 0.f;
        acc[j].x = w0 * hf.x;
        acc[j].y = w0 * hf.y;
    }

    for (int cb = base; cb < end; cb += SE_CAP) {
        int ce = cb + SE_CAP; if (ce > end) ce = end;
        int cn = ce - cb;
        for (int i = lane; i < cn; i += 64) se[i] = csr[cb + i];
        __builtin_amdgcn_wave_barrier();
#pragma unroll
        for (int j = 0; j < 8; j++) {
            int lo = rp[j] < cb ? cb : rp[j];
            int hi = rp[j + 1] > ce ? ce : rp[j + 1];
            int i = lo - cb, iend = hi - cb;
            // 4 edges (2 pairs) per iteration
            for (; i + 3 < iend; i += 4) {
                int2 ra = se[i + sub], rb = se[i + 2 + sub];
                float2 fa = __half22float2(h2[(long)ra.x * 32 + fl]);
                float2 fb = __half22float2(h2[(long)rb.x * 32 + fl]);
                float na = __int_as_float(ra.y), nbm = __int_as_float(rb.y);
                acc[j].x += na * fa.x;  acc[j].y += na * fa.y;
                acc[j].x += nbm * fb.x; acc[j].y += nbm * fb.y;
            }
            if (i + 1 < iend) {   // 2-edge step
                int2 r = se[i + sub];
                float2 f = __half22float2(h2[(long)r.x * 32 + fl]);
                float nm = __int_as_float(r.y);
                acc[j].x += nm * f.x; acc[j].y += nm * f.y;
                i += 2;
            }
            if (i < iend) {       // odd tail: sub0 only
                int2 r = se[i];
                float2 f = __half22float2(h2[(long)r.x * 32 + fl]);
                float nm = (sub == 0) ? __int_as_float(r.y) : 0.f;
                acc[j].x += nm * f.x; acc[j].y += nm * f.y;
            }
        }
        __builtin_amdgcn_wave_barrier();
    }

#pragma unroll
    for (int j = 0; j < 8; j++) {
        acc[j].x += __shfl_xor(acc[j].x, 32);
        acc[j].y += __shfl_xor(acc[j].y, 32);
    }

    if (!WEP) {
        float2 bv = ((const float2*)b)[fl];
        if (sub == 0) {
#pragma unroll
            for (int j = 0; j < 8; j++) {
                float ox = fmaxf(acc[j].x + bv.x, 0.f);
                float oy = fmaxf(acc[j].y + bv.y, 0.f);
                ((__half2*)outp)[(long)(n0w + j) * 32 + fl] = __floats2half2_rn(ox, oy);
            }
        }
        return;
    }

    if (sub == 0) {
        __half2* G2 = (__half2*)G;
#pragma unroll
        for (int j = 0; j < 8; j++)
            G2[(wv * 8 + j) * (G_STRIDE / 2) + fl] = __floats2half2_rn(acc[j].x, acc[j].y);
    }
    __syncthreads();

    // ---- MFMA epilogue: O[32x64] = G @ (W_hi + W_lo) + b ----
    int col = lane & 15, quad = lane >> 4;
    int mrow = (wv & 1) * 16;
    int nc0 = (wv >> 1) * 32;

    half8 af[2];
#pragma unroll
    for (int kt = 0; kt < 2; kt++)
        af[kt] = *(const half8*)&G[(mrow + col) * G_STRIDE + kt * 32 + quad * 8];

    f32x4 c0, c1;
    {
        float b0v = b[nc0 + col], b1v = b[nc0 + 16 + col];
        c0 = (f32x4){b0v, b0v, b0v, b0v};
        c1 = (f32x4){b1v, b1v, b1v, b1v};
    }
#pragma unroll
    for (int nt = 0; nt < 2; nt++) {
        int nidx = nc0 + nt * 16 + col;
#pragma unroll
        for (int kt = 0; kt < 2; kt++) {
            int off = nidx * 64 + kt * 32 + quad * 8;
            half8 bh = *(const half8*)&whi[off];
            half8 bl_ = *(const half8*)&wlo[off];
            if (nt == 0) {
                c0 = __builtin_amdgcn_mfma_f32_16x16x32_f16(af[kt], bh, c0, 0, 0, 0);
                c0 = __builtin_amdgcn_mfma_f32_16x16x32_f16(af[kt], bl_, c0, 0, 0, 0);
            } else {
                c1 = __builtin_amdgcn_mfma_f32_16x16x32_f16(af[kt], bh, c1, 0, 0, 0);
                c1 = __builtin_amdgcn_mfma_f32_16x16x32_f16(af[kt], bl_, c1, 0, 0, 0);
            }
        }
    }

    // C/D: col = lane&15, row = quad*4 + reg
#pragma unroll
    for (int nt = 0; nt < 2; nt++) {
        f32x4 c = nt ? c1 : c0;
#pragma unroll
        for (int r = 0; r < 4; r++) {
            long node = nb + mrow + quad * 4 + r;
            int feat = nc0 + nt * 16 + col;
            float o = c[r];
            if (SIG) {
                o = 1.0f / (1.0f + expf(-o));
                ((float*)outp)[node * 64 + feat] = o;
            } else {
                o = fmaxf(o, 0.f);  // relu at producer
                ((__half*)outp)[node * 64 + feat] = __float2half(o);
            }
        }
    }
}

// ---------------- launch ----------------

extern "C" void kernel_launch(void* const* d_in, const int* in_sizes, int n_in,
                              void* d_out, int out_size, void* d_ws, size_t ws_size,
                              hipStream_t stream) {
    const float* x  = (const float*)d_in[0];
    const int*   ei = (const int*)  d_in[1];
    const float* ew = (const float*)d_in[2];
    const float* W0 = (const float*)d_in[3];
    const float* b0 = (const float*)d_in[4];
    const float* Wm = (const float*)d_in[5];
    const float* bm = (const float*)d_in[6];
    const float* Wl = (const float*)d_in[7];
    const float* bl = (const float*)d_in[8];
    float* out = (float*)d_out;

    const int* src = ei;
    const int* dst = ei + N_EDGES;

    char* ws = (char*)d_ws;
    unsigned long long* packed = (unsigned long long*)(ws + 0);        // 800 KB
    float*    dinv   = (float*)   (ws + (1u  << 20));                  // 400 KB
    int*      rowptr = (int*)     (ws + (2u  << 20));                  // 400 KB
    int*      bsum   = (int*)     (ws + (3u  << 20));                  // 2 KB
    int*      ord    = (int*)     (ws + (3u  << 20) + 65536);          // 6.4 MB
    int2*     csr    = (int2*)    (ws + (10u << 20));                  // 12.8 MB
    _Float16* wt_hi  = (_Float16*)(ws + (23u << 20));                  // 56 KB
    _Float16* wt_lo  = (_Float16*)(ws + (23u << 20) + (1u << 19));     // 56 KB
    __half*   htmp   = (__half*)  (ws + (24u << 20));                  // 12.8 MB
    __half*   hA     = (__half*)  (ws + (37u << 20));                  // 12.8 MB
    __half*   hB     = (__half*)  (ws + (50u << 20));                  // 12.8 MB

    const int BT = 256;
    dim3 blk(BT);
    int gN  = NB_NODES;                       // 391
    int gE  = (N_EDGES + BT - 1) / BT;        // 6250
    int gR4 = (N_NODES + 3) / 4;              // 25000 (gemm0)
    int gG  = N_NODES / 32;                   // 3125 (gather: 32 nodes/block)
    int gP  = (7 * 4096 + BT - 1) / BT;       // 112 (prepw)

    const size_t smem0 = 4 * SE_CAP * 8;                          // 8 KB
    const size_t smemW = 4 * SE_CAP * 8 + 32 * G_STRIDE * 2;      // 12.5 KB

    // prelude
    hipLaunchKernelGGL(k_initp,   dim3(gN), blk, 0, stream, packed);
    hipLaunchKernelGGL(k_cnt,     dim3(gE), blk, 0, stream, dst, ew, packed, ord);
    hipLaunchKernelGGL(k_part,    dim3(gN), blk, 0, stream, packed, bsum, dinv);
    hipLaunchKernelGGL(k_scanb,   dim3(1), dim3(512), 0, stream, bsum, rowptr);
    hipLaunchKernelGGL(k_fillptr, dim3(gN), blk, 0, stream, packed, bsum, rowptr);
    hipLaunchKernelGGL(k_fill,    dim3(gE), blk, 0, stream, src, dst, ew, dinv, rowptr, ord, csr);
    hipLaunchKernelGGL(k_prepw,   dim3(gP), blk, 0, stream, Wm, Wl, wt_hi, wt_lo);

    // layer 0
    hipLaunchKernelGGL(k_gemm0,   dim3(gR4), blk, 0, stream, x, W0, htmp);
    hipLaunchKernelGGL((k_gather5<false, false>), dim3(gG), blk, smem0, stream,
                       rowptr, csr, htmp, dinv, (const _Float16*)nullptr,
                       (const _Float16*)nullptr, b0, (void*)hA);

    // middle layers 1..6
    __half* hin = hA;
    __half* hout = hB;
    for (int i = 0; i < 6; i++) {
        const float* bi = bm + (long)i * 64;
        hipLaunchKernelGGL((k_gather5<true, false>), dim3(gG), blk, smemW, stream,
                           rowptr, csr, hin, dinv, wt_hi + (long)i * 4096,
                           wt_lo + (long)i * 4096, bi, (void*)hout);
        __half* t2 = hin; hin = hout; hout = t2;
    }

    // final layer + sigmoid -> fp32 d_out
    hipLaunchKernelGGL((k_gather5<true, true>), dim3(gG), blk, smemW, stream,
                       rowptr, csr, hin, dinv, wt_hi + 6l * 4096, wt_lo + 6l * 4096,
                       bl, (void*)out);
}

// Round 9
// 565.849 us; speedup vs baseline: 1.1413x; 1.1413x over previous
//
#include <hip/hip_runtime.h>
#include <hip/hip_fp16.h>
#include <math.h>

#define N_NODES 100000
#define N_EDGES 1600000
#define F_IN 15
#define NB_NODES 391   // ceil(N_NODES/256)
#define MASK40 ((1ull << 40) - 1)

typedef _Float16 half8 __attribute__((ext_vector_type(8)));
typedef float f32x4 __attribute__((ext_vector_type(4)));

// ---------------- fused front: cnt (atomic) + gemm0 + prepw ------------------
// k_cnt is coherence-bound (1% VALU, 10% BW) — gemm0/prepw blocks fill the
// idle CUs. Interleave: b%5==0 -> cnt (6250), b>=31250 -> prepw (112),
// else gemm0 (25000). packed[] must be zeroed beforehand (hipMemsetAsync).

__global__ __launch_bounds__(256) void k_front(
        const int* __restrict__ dst, const float* __restrict__ ew,
        unsigned long long* __restrict__ packed, int* __restrict__ ord,
        const float* __restrict__ x, const float* __restrict__ W0,
        __half* __restrict__ htmp,
        const float* __restrict__ Wm, const float* __restrict__ Wl,
        _Float16* __restrict__ wt_hi, _Float16* __restrict__ wt_lo) {
    __shared__ float Ws[F_IN * 64];
    int b = blockIdx.x;
    int t = threadIdx.x;

    if (b >= 31250) {
        // prepw: transposed n-major fp16 hi/lo split of Wm(6)+Wl(1).
        // 112 blocks x 256 = 28672 = 7*4096 exactly.
        int i = (b - 31250) * 256 + t;
        int l = i >> 12, n = (i >> 6) & 63, k = i & 63;
        float w = (l < 6) ? Wm[l * 4096 + k * 64 + n] : Wl[k * 64 + n];
        _Float16 hi = (_Float16)w;
        wt_hi[i] = hi;
        wt_lo[i] = (_Float16)(w - (float)hi);
        return;
    }
    if (b % 5 == 0) {
        // cnt: one packed 64-bit atomic per edge; count in [40..], weight-sum
        // 32.8fx below. Returned old count = this edge's CSR ordinal.
        int i = (b / 5) * 256 + t;   // 6250*256 = N_EDGES exactly
        int d = dst[i];
        unsigned long long contrib =
            (1ull << 40) + (unsigned long long)((double)ew[i] * 4294967296.0);
        unsigned long long old = atomicAdd(&packed[d], contrib);
        ord[i] = (int)(old >> 40);
        return;
    }
    // gemm0: [N,15]@[15,64] -> fp16 (pre-activation), 4 rows/block
    int gb = b - b / 5 - 1;          // [0, 25000)
    for (int i = t; i < F_IN * 64; i += 256) Ws[i] = W0[i];
    __syncthreads();
    int r = gb * 4 + (t >> 6);
    int c = t & 63;
    if (r < N_NODES) {
        const float* xr = x + (long)r * F_IN;
        float acc = 0.f;
#pragma unroll
        for (int k = 0; k < F_IN; k++) acc += xr[k] * Ws[k * 64 + c];
        htmp[(long)r * 64 + c] = __float2half(acc);
    }
}

// ---------------- scan chain ----------------

__global__ void k_part(const unsigned long long* __restrict__ packed,
                       int* __restrict__ bsum, float* __restrict__ dinv) {
    __shared__ int red[256];
    int t = threadIdx.x;
    int i = blockIdx.x * 256 + t;
    int c = 0;
    if (i < N_NODES) {
        unsigned long long p = packed[i];
        c = (int)(p >> 40);
        float deg = 1.0f + (float)((double)(p & MASK40) * 0x1p-32);
        dinv[i] = rsqrtf(deg);
    }
    red[t] = c;
    __syncthreads();
    for (int off = 128; off > 0; off >>= 1) {
        if (t < off) red[t] += red[t + off];
        __syncthreads();
    }
    if (t == 0) bsum[blockIdx.x] = red[0];
}

__global__ __launch_bounds__(512) void k_scanb(int* __restrict__ bsum,
                                               int* __restrict__ rowptr) {
    __shared__ int sc[512];
    int t = threadIdx.x;
    int v = (t < NB_NODES) ? bsum[t] : 0;
    sc[t] = v;
    __syncthreads();
    for (int off = 1; off < 512; off <<= 1) {
        int u = (t >= off) ? sc[t - off] : 0;
        __syncthreads();
        sc[t] += u;
        __syncthreads();
    }
    if (t < NB_NODES) bsum[t] = sc[t] - v;
    if (t == 0) rowptr[N_NODES] = N_EDGES;
}

__global__ void k_fillptr(const unsigned long long* __restrict__ packed,
                          const int* __restrict__ bsum, int* __restrict__ rowptr) {
    __shared__ int sc[256];
    int t = threadIdx.x;
    int i = blockIdx.x * 256 + t;
    int v = (i < N_NODES) ? (int)(packed[i] >> 40) : 0;
    sc[t] = v;
    __syncthreads();
    for (int off = 1; off < 256; off <<= 1) {
        int u = (t >= off) ? sc[t - off] : 0;
        __syncthreads();
        sc[t] += u;
        __syncthreads();
    }
    if (i < N_NODES) rowptr[i] = bsum[blockIdx.x] + sc[t] - v;
}

__global__ void k_fill(const int* __restrict__ src, const int* __restrict__ dst,
                       const float* __restrict__ w, const float* __restrict__ dinv,
                       const int* __restrict__ rowptr, const int* __restrict__ ord,
                       int2* __restrict__ csr) {
    int i = blockIdx.x * blockDim.x + threadIdx.x;
    if (i >= N_EDGES) return;
    int s = src[i], d = dst[i];
    float nm = dinv[s] * w[i] * dinv[d];
    csr[rowptr[d] + ord[i]] = make_int2(s, __float_as_int(nm));
}

// ---------------- fused aggregation + MFMA dense epilogue --------------------
// hin stored POST-activation. Wave = 8 nodes; lane = (sub: edge-of-pair) x
// (fl: feature pair). Records LDS-staged. 8-edge main unroll = 4 pair-loads
// in flight per lane — R7/R8 A/B proved gather time tracks loads-in-flight
// (4->2 in flight cost +11 µs/dispatch). Do not reduce.

#define SE_CAP 256
#define G_STRIDE 72

template <bool WEP, bool SIG>
__global__ __launch_bounds__(256) void k_gather5(
        const int* __restrict__ rowptr, const int2* __restrict__ csr,
        const __half* __restrict__ hin, const float* __restrict__ dinv,
        const _Float16* __restrict__ whi, const _Float16* __restrict__ wlo,
        const float* __restrict__ b, void* __restrict__ outp) {
    extern __shared__ char smem[];
    int t = threadIdx.x, wv = t >> 6, lane = t & 63;
    int sub = lane >> 5, fl = lane & 31;
    int2* se = (int2*)smem + wv * SE_CAP;
    _Float16* G = (_Float16*)(smem + 4 * SE_CAP * 8);

    int nb = blockIdx.x * 32;
    int n0w = nb + wv * 8;

    int rp[9];
#pragma unroll
    for (int j = 0; j < 9; j++) rp[j] = rowptr[n0w + j];
    int base = rp[0], end = rp[8];

    const __half2* h2 = (const __half2*)hin;

    float2 acc[8];
#pragma unroll
    for (int j = 0; j < 8; j++) {
        int n = n0w + j;
        float dv = dinv[n];
        float2 hf = __half22float2(h2[(long)n * 32 + fl]);
        float w0 = (sub == 0) ? dv * dv : 0.f;
        acc[j].x = w0 * hf.x;
        acc[j].y = w0 * hf.y;
    }

    for (int cb = base; cb < end; cb += SE_CAP) {
        int ce = cb + SE_CAP; if (ce > end) ce = end;
        int cn = ce - cb;
        for (int i = lane; i < cn; i += 64) se[i] = csr[cb + i];
        __builtin_amdgcn_wave_barrier();
#pragma unroll
        for (int j = 0; j < 8; j++) {
            int lo = rp[j] < cb ? cb : rp[j];
            int hi = rp[j + 1] > ce ? ce : rp[j + 1];
            int i = lo - cb, iend = hi - cb;
            // 8 edges (4 pairs) per iteration: 4 loads/lane in flight
            for (; i + 7 < iend; i += 8) {
                int2 r0 = se[i + sub],     r1 = se[i + 2 + sub];
                int2 r2 = se[i + 4 + sub], r3 = se[i + 6 + sub];
                float2 f0 = __half22float2(h2[(long)r0.x * 32 + fl]);
                float2 f1 = __half22float2(h2[(long)r1.x * 32 + fl]);
                float2 f2 = __half22float2(h2[(long)r2.x * 32 + fl]);
                float2 f3 = __half22float2(h2[(long)r3.x * 32 + fl]);
                float n0 = __int_as_float(r0.y), n1 = __int_as_float(r1.y);
                float n2 = __int_as_float(r2.y), n3 = __int_as_float(r3.y);
                acc[j].x += n0 * f0.x; acc[j].y += n0 * f0.y;
                acc[j].x += n1 * f1.x; acc[j].y += n1 * f1.y;
                acc[j].x += n2 * f2.x; acc[j].y += n2 * f2.y;
                acc[j].x += n3 * f3.x; acc[j].y += n3 * f3.y;
            }
            for (; i + 1 < iend; i += 2) {
                int2 r = se[i + sub];
                float2 f = __half22float2(h2[(long)r.x * 32 + fl]);
                float nm = __int_as_float(r.y);
                acc[j].x += nm * f.x; acc[j].y += nm * f.y;
            }
            if (i < iend) {       // odd tail: sub0 only
                int2 r = se[i];
                float2 f = __half22float2(h2[(long)r.x * 32 + fl]);
                float nm = (sub == 0) ? __int_as_float(r.y) : 0.f;
                acc[j].x += nm * f.x; acc[j].y += nm * f.y;
            }
        }
        __builtin_amdgcn_wave_barrier();
    }

#pragma unroll
    for (int j = 0; j < 8; j++) {
        acc[j].x += __shfl_xor(acc[j].x, 32);
        acc[j].y += __shfl_xor(acc[j].y, 32);
    }

    if (!WEP) {
        float2 bv = ((const float2*)b)[fl];
        if (sub == 0) {
#pragma unroll
            for (int j = 0; j < 8; j++) {
                float ox = fmaxf(acc[j].x + bv.x, 0.f);
                float oy = fmaxf(acc[j].y + bv.y, 0.f);
                ((__half2*)outp)[(long)(n0w + j) * 32 + fl] = __floats2half2_rn(ox, oy);
            }
        }
        return;
    }

    if (sub == 0) {
        __half2* G2 = (__half2*)G;
#pragma unroll
        for (int j = 0; j < 8; j++)
            G2[(wv * 8 + j) * (G_STRIDE / 2) + fl] = __floats2half2_rn(acc[j].x, acc[j].y);
    }
    __syncthreads();

    // ---- MFMA epilogue: O[32x64] = G @ (W_hi + W_lo) + b ----
    int col = lane & 15, quad = lane >> 4;
    int mrow = (wv & 1) * 16;
    int nc0 = (wv >> 1) * 32;

    half8 af[2];
#pragma unroll
    for (int kt = 0; kt < 2; kt++)
        af[kt] = *(const half8*)&G[(mrow + col) * G_STRIDE + kt * 32 + quad * 8];

    f32x4 c0, c1;
    {
        float b0v = b[nc0 + col], b1v = b[nc0 + 16 + col];
        c0 = (f32x4){b0v, b0v, b0v, b0v};
        c1 = (f32x4){b1v, b1v, b1v, b1v};
    }
#pragma unroll
    for (int nt = 0; nt < 2; nt++) {
        int nidx = nc0 + nt * 16 + col;
#pragma unroll
        for (int kt = 0; kt < 2; kt++) {
            int off = nidx * 64 + kt * 32 + quad * 8;
            half8 bh = *(const half8*)&whi[off];
            half8 bl_ = *(const half8*)&wlo[off];
            if (nt == 0) {
                c0 = __builtin_amdgcn_mfma_f32_16x16x32_f16(af[kt], bh, c0, 0, 0, 0);
                c0 = __builtin_amdgcn_mfma_f32_16x16x32_f16(af[kt], bl_, c0, 0, 0, 0);
            } else {
                c1 = __builtin_amdgcn_mfma_f32_16x16x32_f16(af[kt], bh, c1, 0, 0, 0);
                c1 = __builtin_amdgcn_mfma_f32_16x16x32_f16(af[kt], bl_, c1, 0, 0, 0);
            }
        }
    }

    // C/D: col = lane&15, row = quad*4 + reg
#pragma unroll
    for (int nt = 0; nt < 2; nt++) {
        f32x4 c = nt ? c1 : c0;
#pragma unroll
        for (int r = 0; r < 4; r++) {
            long node = nb + mrow + quad * 4 + r;
            int feat = nc0 + nt * 16 + col;
            float o = c[r];
            if (SIG) {
                o = 1.0f / (1.0f + expf(-o));
                ((float*)outp)[node * 64 + feat] = o;
            } else {
                o = fmaxf(o, 0.f);  // relu at producer
                ((__half*)outp)[node * 64 + feat] = __float2half(o);
            }
        }
    }
}

// ---------------- launch ----------------

extern "C" void kernel_launch(void* const* d_in, const int* in_sizes, int n_in,
                              void* d_out, int out_size, void* d_ws, size_t ws_size,
                              hipStream_t stream) {
    const float* x  = (const float*)d_in[0];
    const int*   ei = (const int*)  d_in[1];
    const float* ew = (const float*)d_in[2];
    const float* W0 = (const float*)d_in[3];
    const float* b0 = (const float*)d_in[4];
    const float* Wm = (const float*)d_in[5];
    const float* bm = (const float*)d_in[6];
    const float* Wl = (const float*)d_in[7];
    const float* bl = (const float*)d_in[8];
    float* out = (float*)d_out;

    const int* src = ei;
    const int* dst = ei + N_EDGES;

    char* ws = (char*)d_ws;
    unsigned long long* packed = (unsigned long long*)(ws + 0);        // 800 KB
    float*    dinv   = (float*)   (ws + (1u  << 20));                  // 400 KB
    int*      rowptr = (int*)     (ws + (2u  << 20));                  // 400 KB
    int*      bsum   = (int*)     (ws + (3u  << 20));                  // 2 KB
    int*      ord    = (int*)     (ws + (3u  << 20) + 65536);          // 6.4 MB
    int2*     csr    = (int2*)    (ws + (10u << 20));                  // 12.8 MB
    _Float16* wt_hi  = (_Float16*)(ws + (23u << 20));                  // 56 KB
    _Float16* wt_lo  = (_Float16*)(ws + (23u << 20) + (1u << 19));     // 56 KB
    __half*   htmp   = (__half*)  (ws + (24u << 20));                  // 12.8 MB
    __half*   hA     = (__half*)  (ws + (37u << 20));                  // 12.8 MB
    __half*   hB     = (__half*)  (ws + (50u << 20));                  // 12.8 MB

    const int BT = 256;
    dim3 blk(BT);
    int gN  = NB_NODES;                  // 391
    int gE  = (N_EDGES + BT - 1) / BT;   // 6250
    int gF  = 31250 + 112;               // front: 6250 cnt + 25000 gemm0 + 112 prepw
    int gG  = N_NODES / 32;              // 3125 (gather: 32 nodes/block)

    const size_t smem0 = 4 * SE_CAP * 8;                          // 8 KB
    const size_t smemW = 4 * SE_CAP * 8 + 32 * G_STRIDE * 2;      // 12.5 KB

    // zero the packed histogram (stream op: graph-capturable)
    hipMemsetAsync(packed, 0, (size_t)N_NODES * 8, stream);

    // fused front: cnt atomics + gemm0 + prepw in one dispatch
    hipLaunchKernelGGL(k_front, dim3(gF), blk, 0, stream,
                       dst, ew, packed, ord, x, W0, htmp, Wm, Wl, wt_hi, wt_lo);

    // scan chain + CSR fill
    hipLaunchKernelGGL(k_part,    dim3(gN), blk, 0, stream, packed, bsum, dinv);
    hipLaunchKernelGGL(k_scanb,   dim3(1), dim3(512), 0, stream, bsum, rowptr);
    hipLaunchKernelGGL(k_fillptr, dim3(gN), blk, 0, stream, packed, bsum, rowptr);
    hipLaunchKernelGGL(k_fill,    dim3(gE), blk, 0, stream, src, dst, ew, dinv, rowptr, ord, csr);

    // layer 0 aggregation (no W epilogue): htmp -> hA, relu at store
    hipLaunchKernelGGL((k_gather5<false, false>), dim3(gG), blk, smem0, stream,
                       rowptr, csr, htmp, dinv, (const _Float16*)nullptr,
                       (const _Float16*)nullptr, b0, (void*)hA);

    // middle layers 1..6: fused (A h) W + b via MFMA, relu at store
    __half* hin = hA;
    __half* hout = hB;
    for (int i = 0; i < 6; i++) {
        const float* bi = bm + (long)i * 64;
        hipLaunchKernelGGL((k_gather5<true, false>), dim3(gG), blk, smemW, stream,
                           rowptr, csr, hin, dinv, wt_hi + (long)i * 4096,
                           wt_lo + (long)i * 4096, bi, (void*)hout);
        __half* t2 = hin; hin = hout; hout = t2;
    }

    // final layer + sigmoid -> fp32 d_out
    hipLaunchKernelGGL((k_gather5<true, true>), dim3(gG), blk, smemW, stream,
                       rowptr, csr, hin, dinv, wt_hi + 6l * 4096, wt_lo + 6l * 4096,
                       bl, (void*)out);
}